// Round 10
// baseline (374.421 us; speedup 1.0000x reference)
//
#include <hip/hip_runtime.h>
#include <hip/hip_bf16.h>

#define ED 128
#define RR 8
#define LDB 136          // LDS row stride in shorts (128 data + 8 pad)

typedef __attribute__((ext_vector_type(8))) short short8;   // 8 x bf16
typedef __attribute__((ext_vector_type(4))) float f32x4;    // MFMA accumulator
typedef __attribute__((ext_vector_type(4))) unsigned short u16x4;

#define RL(v, i) __builtin_amdgcn_readlane(v, i)

__device__ __forceinline__ unsigned short f2bf(float f){
  unsigned int u = __builtin_bit_cast(unsigned int, f);
  return (unsigned short)((u + 0x7fffu + ((u >> 16) & 1u)) >> 16);   // RNE
}
__device__ __forceinline__ float bf2f(unsigned int lo){
  return __builtin_bit_cast(float, lo << 16);
}
__device__ __forceinline__ unsigned int packbf(float hi, float lo){
  return ((unsigned int)f2bf(hi) << 16) | f2bf(lo);
}

// ---- cast f32 -> bf16, 4 at a time; NT load (x is read exactly once) ----
__global__ void cast_bf16_vec(const float* __restrict__ in, unsigned short* __restrict__ out, int n4){
  int stride = gridDim.x * blockDim.x;
  for (int i = blockIdx.x * blockDim.x + threadIdx.x; i < n4; i += stride){
    f32x4 v = __builtin_nontemporal_load((const f32x4*)(in + (size_t)i * 4));
    u16x4 o;
    o[0] = f2bf(v[0]); o[1] = f2bf(v[1]); o[2] = f2bf(v[2]); o[3] = f2bf(v[3]);
    *(u16x4*)(out + (size_t)i * 4) = o;          // normal store: xb/wbb stay cached
  }
}

// ---- single atomic pass: histogram + per-edge rank ----
__global__ void hist_rank(const int* __restrict__ rel, const int* __restrict__ dst,
                          int* __restrict__ rowcnt, int* __restrict__ rank, int E){
  int stride = gridDim.x * blockDim.x;
  for (int i = blockIdx.x * blockDim.x + threadIdx.x; i < E; i += stride)
    rank[i] = atomicAdd(&rowcnt[(dst[i] << 3) | rel[i]], 1);
}

// ---- scan step 1: per-block (1024) sums ----
__launch_bounds__(1024)
__global__ void scan_block_sum(const int* __restrict__ rowcnt, int* __restrict__ bsum, int m){
  __shared__ int lds[16];
  int t = threadIdx.x;
  int idx = blockIdx.x * 1024 + t;
  int v = (idx < m) ? rowcnt[idx] : 0;
#pragma unroll
  for (int o = 32; o > 0; o >>= 1) v += __shfl_down(v, o);
  if ((t & 63) == 0) lds[t >> 6] = v;
  __syncthreads();
  if (t == 0){
    int s = 0;
#pragma unroll
    for (int w = 0; w < 16; ++w) s += lds[w];
    bsum[blockIdx.x] = s;
  }
}

// ---- scan step 2: PARALLEL exclusive scan of block sums (nb <= 1024) ----
__launch_bounds__(1024)
__global__ void scan_bsum_par(const int* __restrict__ bsum, int* __restrict__ bscan,
                              int nb, int* __restrict__ total_out){
  __shared__ int wsum[16];
  int t = threadIdx.x, lane = t & 63, wid = t >> 6;
  int v = (t < nb) ? bsum[t] : 0;
  int incl = v;
#pragma unroll
  for (int o = 1; o < 64; o <<= 1){
    int u = __shfl_up(incl, o);
    if (lane >= o) incl += u;
  }
  if (lane == 63) wsum[wid] = incl;
  __syncthreads();
  int woff = 0;
  for (int w0 = 0; w0 < wid; ++w0) woff += wsum[w0];
  if (t < nb) bscan[t] = woff + incl - v;
  if (t == nb - 1) *total_out = woff + incl;     // row_ptr[m] = E
}

// ---- scan step 3: wave-scan + cross-wave offset (1 barrier) ----
__launch_bounds__(1024)
__global__ void scan_final(const int* __restrict__ rowcnt, const int* __restrict__ bscan,
                           int* __restrict__ row_ptr, int m){
  __shared__ int wsum[16];
  int t = threadIdx.x, lane = t & 63, wid = t >> 6;
  int idx = blockIdx.x * 1024 + t;
  int v = (idx < m) ? rowcnt[idx] : 0;
  int incl = v;
#pragma unroll
  for (int o = 1; o < 64; o <<= 1){
    int u = __shfl_up(incl, o);
    if (lane >= o) incl += u;
  }
  if (lane == 63) wsum[wid] = incl;
  __syncthreads();
  int woff = bscan[blockIdx.x];
  for (int w0 = 0; w0 < wid; ++w0) woff += wsum[w0];
  if (idx < m) row_ptr[idx] = woff + incl - v;   // exclusive
}

// ---- atomic-free bucket write: pos = row_ptr[key] + rank ----
__global__ void scatter_pos(const int* __restrict__ rel, const int* __restrict__ src,
                            const int* __restrict__ dst, const int* __restrict__ rank,
                            const int* __restrict__ row_ptr, int* __restrict__ payload, int E){
  int stride = gridDim.x * blockDim.x;
  for (int i = blockIdx.x * blockDim.x + threadIdx.x; i < E; i += stride){
    int key = (dst[i] << 3) | rel[i];
    payload[row_ptr[key] + rank[i]] = src[i];
  }
}

// ---- fused aggregate + transform: 128-node tile, 1024 threads (16 waves).
// Wave owns 8 nodes. Per relation r: 16-deep batched gathers -> h_r row in regs,
// B_r reg-prefetch; barrier; h_r+B_r -> LDS; barrier; 16 MFMA (K=128 chunk).
// h2 never goes to HBM. out = relu(acc) written NT.
__launch_bounds__(1024, 8)
__global__ void fused_agg_gemm(const unsigned short* __restrict__ xb,
                               const unsigned short* __restrict__ wbb,
                               const int* __restrict__ row_ptr8,
                               const int* __restrict__ payload,
                               float* __restrict__ out, int n, int m){
  __shared__ __align__(16) unsigned short lds_h[128 * LDB];   // 34 KB
  __shared__ __align__(16) unsigned short lds_b[128 * LDB];   // 34 KB
  const int t = threadIdx.x;
  const int wave = t >> 6, lane = t & 63;
  const int dbase = blockIdx.x << 7;
  const int nb = dbase + (wave << 3);          // wave's first node
  const int frow = lane & 15, kb = lane >> 4;
  const int mr = wave >> 2, nc = wave & 3;     // 4x4 wave grid, 32x32 out tile each

  // ---- once per wave: all 64 row boundaries + 3 payload windows ----
  int rowi = (nb << 3) + lane; if (rowi > m) rowi = m;   // OOB nodes -> cnt 0
  int pv = row_ptr8[rowi];
  int rowe = (nb << 3) + 64; if (rowe > m) rowe = m;
  int lastb = row_ptr8[rowe];
  int wbase = RL(pv, 0);
  int pl0 = payload[wbase + lane];             // spills past E land in row_ptr (safe)
  int pl1 = payload[wbase + 64 + lane];
  int pl2 = payload[wbase + 128 + lane];

  f32x4 acc[2][2];
#pragma unroll
  for (int rt = 0; rt < 2; ++rt)
#pragma unroll
    for (int jt = 0; jt < 2; ++jt)
      acc[rt][jt] = (f32x4){0.f, 0.f, 0.f, 0.f};

  for (int r = 0; r < RR; ++r){
    // segment [sg, sg+dg) per node for this r (all SGPR scalars)
    int sg[8], dg[8];
#pragma unroll
    for (int i = 0; i < 8; ++i){
      int bi = RL(pv, (i << 3) + r);
      int ei = ((i << 3) + r + 1) < 64 ? RL(pv, (i << 3) + r + 1) : lastb;
      sg[i] = bi - wbase;
      dg[i] = ei - bi;
    }
    int dmax = dg[0];
#pragma unroll
    for (int i = 1; i < 8; ++i) dmax = dg[i] > dmax ? dg[i] : dmax;

    float ax[8], ay[8];
#pragma unroll
    for (int i = 0; i < 8; ++i){ ax[i] = 0.f; ay[i] = 0.f; }

#define SRC(IDX) ((IDX) < 64 ? RL(pl0, (IDX)) : (IDX) < 128 ? RL(pl1, (IDX) - 64) \
                 : (IDX) < 192 ? RL(pl2, (IDX) - 128) : payload[wbase + (IDX)])

    for (int j = 0; j < dmax; j += 2){         // 2 ranks x 8 nodes: 16 loads in flight
      unsigned va[8], vb[8];
#pragma unroll
      for (int i = 0; i < 8; ++i){
        if (j < dg[i]){
          int s = SRC(sg[i] + j);
          va[i] = ((const unsigned*)(xb + ((size_t)s << 7)))[lane];
        }
        if (j + 1 < dg[i]){
          int s = SRC(sg[i] + j + 1);
          vb[i] = ((const unsigned*)(xb + ((size_t)s << 7)))[lane];
        }
      }
#pragma unroll
      for (int i = 0; i < 8; ++i){
        if (j < dg[i])    { ax[i] += bf2f(va[i] & 0xffffu); ay[i] += bf2f(va[i] >> 16); }
        if (j + 1 < dg[i]){ ax[i] += bf2f(vb[i] & 0xffffu); ay[i] += bf2f(vb[i] >> 16); }
      }
    }
#undef SRC

    // B_r prefetch to registers (issue before barrier; latency hides under it)
    const unsigned short* wp = wbb + (r << 14);
    const int brow = t >> 3, bcol = (t & 7) << 4;
    short8 pb0 = *(const short8*)(wp + brow * ED + bcol);
    short8 pb1 = *(const short8*)(wp + brow * ED + bcol + 8);

    __syncthreads();                           // prev MFMA done reading LDS
#pragma unroll
    for (int i = 0; i < 8; ++i){
      float sc = dg[i] > 0 ? 1.f / (float)dg[i] : 0.f;
      ((unsigned*)lds_h)[((wave << 3) + i) * (LDB / 2) + lane] = packbf(ay[i] * sc, ax[i] * sc);
    }
    *(short8*)&lds_b[brow * LDB + bcol] = pb0;
    *(short8*)&lds_b[brow * LDB + bcol + 8] = pb1;
    __syncthreads();                           // h_r, B_r ready

    // MFMA: 32x32 wave tile x K=128 chunk
#pragma unroll
    for (int ks = 0; ks < 4; ++ks){
      short8 a0 = *(const short8*)&lds_h[(mr * 32 + frow) * LDB + ks * 32 + kb * 8];
      short8 a1 = *(const short8*)&lds_h[(mr * 32 + 16 + frow) * LDB + ks * 32 + kb * 8];
      short8 b0 = *(const short8*)&lds_b[(nc * 32 + frow) * LDB + ks * 32 + kb * 8];
      short8 b1 = *(const short8*)&lds_b[(nc * 32 + 16 + frow) * LDB + ks * 32 + kb * 8];
      acc[0][0] = __builtin_amdgcn_mfma_f32_16x16x32_bf16(a0, b0, acc[0][0], 0, 0, 0);
      acc[0][1] = __builtin_amdgcn_mfma_f32_16x16x32_bf16(a0, b1, acc[0][1], 0, 0, 0);
      acc[1][0] = __builtin_amdgcn_mfma_f32_16x16x32_bf16(a1, b0, acc[1][0], 0, 0, 0);
      acc[1][1] = __builtin_amdgcn_mfma_f32_16x16x32_bf16(a1, b1, acc[1][1], 0, 0, 0);
    }
  }

  // ---- epilogue: D layout col = lane&15, row = (lane>>4)*4 + reg ----
  const int drow = (lane >> 4) << 2;
  const int dcol = lane & 15;
#pragma unroll
  for (int rt = 0; rt < 2; ++rt)
#pragma unroll
    for (int jt = 0; jt < 2; ++jt)
#pragma unroll
      for (int reg = 0; reg < 4; ++reg){
        int i = dbase + mr * 32 + rt * 16 + drow + reg;
        if (i < n)
          __builtin_nontemporal_store(fmaxf(acc[rt][jt][reg], 0.f),
                                      &out[(size_t)i * ED + nc * 32 + jt * 16 + dcol]);
      }
}

extern "C" void kernel_launch(void* const* d_in, const int* in_sizes, int n_in,
                              void* d_out, int out_size, void* d_ws, size_t ws_size,
                              hipStream_t stream){
  const float* x  = (const float*)d_in[0];
  const float* w  = (const float*)d_in[1];
  const int* erel = (const int*)d_in[2];
  const int* esrc = (const int*)d_in[3];
  const int* edst = (const int*)d_in[4];
  float* out = (float*)d_out;

  const int n = in_sizes[0] / ED;          // 100000
  const int E = in_sizes[2];               // 1600000
  const int m = n * RR;                    // 800000 CSR rows
  const int NB = (m + 1023) / 1024;        // 782 (must be <= 1024)

  // ---- workspace layout (256B-aligned segments) ----
  char* ws = (char*)d_ws;
  size_t off = 0;
  auto alloc = [&](size_t bytes) -> char* {
    char* p = ws + off;
    off += (bytes + 255) & ~(size_t)255;
    return p;
  };
  unsigned short* xb      = (unsigned short*)alloc((size_t)n * ED * 2);     // 25.6 MB
  unsigned short* wbb     = (unsigned short*)alloc((size_t)RR * ED * ED * 2); // 256 KB
  int*            payload = (int*)alloc((size_t)E * 4);                     // 6.4 MB
  int*            row_ptr = (int*)alloc((size_t)(m + 1) * 4);               // 3.2 MB (pads payload OOB reads)
  int*            rowcnt  = (int*)alloc((size_t)m * 4);
  int*            rank    = (int*)alloc((size_t)E * 4);                     // 6.4 MB
  int*            bsum    = (int*)alloc((size_t)NB * 4);
  int*            bscan   = (int*)alloc((size_t)NB * 4);
  if (off > ws_size || NB > 1024) return;

  (void)hipMemsetAsync(rowcnt, 0, (size_t)m * 4, stream);

  cast_bf16_vec<<<2048, 256, 0, stream>>>(x, xb, n * ED / 4);
  cast_bf16_vec<<<128, 256, 0, stream>>>(w, wbb, RR * ED * ED / 4);
  hist_rank    <<<2048, 256, 0, stream>>>(erel, edst, rowcnt, rank, E);
  scan_block_sum<<<NB, 1024, 0, stream>>>(rowcnt, bsum, m);
  scan_bsum_par<<<1, 1024, 0, stream>>>(bsum, bscan, NB, row_ptr + m);
  scan_final   <<<NB, 1024, 0, stream>>>(rowcnt, bscan, row_ptr, m);
  scatter_pos  <<<2048, 256, 0, stream>>>(erel, esrc, edst, rank, row_ptr, payload, E);
  fused_agg_gemm<<<(n + 127) / 128, 1024, 0, stream>>>(xb, wbb, row_ptr, payload, out, n, m);
}

// Round 11
// 367.386 us; speedup vs baseline: 1.0191x; 1.0191x over previous
//
#include <hip/hip_runtime.h>
#include <hip/hip_bf16.h>

#define ED 128
#define RR 8
#define LDB 136          // LDS row stride in shorts (128 data + 8 pad)

typedef __attribute__((ext_vector_type(8))) short short8;   // 8 x bf16
typedef __attribute__((ext_vector_type(4))) float f32x4;    // MFMA accumulator
typedef __attribute__((ext_vector_type(4))) unsigned short u16x4;

#define RL(v, i) __builtin_amdgcn_readlane(v, i)

__device__ __forceinline__ unsigned short f2bf(float f){
  unsigned int u = __builtin_bit_cast(unsigned int, f);
  return (unsigned short)((u + 0x7fffu + ((u >> 16) & 1u)) >> 16);   // RNE
}
__device__ __forceinline__ float bf2f(unsigned int lo){
  return __builtin_bit_cast(float, lo << 16);
}
__device__ __forceinline__ unsigned int packbf(float hi, float lo){
  return ((unsigned int)f2bf(hi) << 16) | f2bf(lo);
}

// ---- cast f32 -> bf16, 4 at a time; NT load (x is read exactly once) ----
__global__ void cast_bf16_vec(const float* __restrict__ in, unsigned short* __restrict__ out, int n4){
  int stride = gridDim.x * blockDim.x;
  for (int i = blockIdx.x * blockDim.x + threadIdx.x; i < n4; i += stride){
    f32x4 v = __builtin_nontemporal_load((const f32x4*)(in + (size_t)i * 4));
    u16x4 o;
    o[0] = f2bf(v[0]); o[1] = f2bf(v[1]); o[2] = f2bf(v[2]); o[3] = f2bf(v[3]);
    *(u16x4*)(out + (size_t)i * 4) = o;          // normal store: xb/wbb stay cached
  }
}

// ---- single atomic pass: histogram + per-edge rank ----
__global__ void hist_rank(const int* __restrict__ rel, const int* __restrict__ dst,
                          int* __restrict__ rowcnt, int* __restrict__ rank, int E){
  int stride = gridDim.x * blockDim.x;
  for (int i = blockIdx.x * blockDim.x + threadIdx.x; i < E; i += stride)
    rank[i] = atomicAdd(&rowcnt[(dst[i] << 3) | rel[i]], 1);
}

// ---- scan step 1: per-block (1024) sums ----
__launch_bounds__(1024)
__global__ void scan_block_sum(const int* __restrict__ rowcnt, int* __restrict__ bsum, int m){
  __shared__ int lds[16];
  int t = threadIdx.x;
  int idx = blockIdx.x * 1024 + t;
  int v = (idx < m) ? rowcnt[idx] : 0;
#pragma unroll
  for (int o = 32; o > 0; o >>= 1) v += __shfl_down(v, o);
  if ((t & 63) == 0) lds[t >> 6] = v;
  __syncthreads();
  if (t == 0){
    int s = 0;
#pragma unroll
    for (int w = 0; w < 16; ++w) s += lds[w];
    bsum[blockIdx.x] = s;
  }
}

// ---- scan step 2: PARALLEL exclusive scan of block sums (nb <= 1024) ----
__launch_bounds__(1024)
__global__ void scan_bsum_par(const int* __restrict__ bsum, int* __restrict__ bscan,
                              int nb, int* __restrict__ total_out){
  __shared__ int wsum[16];
  int t = threadIdx.x, lane = t & 63, wid = t >> 6;
  int v = (t < nb) ? bsum[t] : 0;
  int incl = v;
#pragma unroll
  for (int o = 1; o < 64; o <<= 1){
    int u = __shfl_up(incl, o);
    if (lane >= o) incl += u;
  }
  if (lane == 63) wsum[wid] = incl;
  __syncthreads();
  int woff = 0;
  for (int w0 = 0; w0 < wid; ++w0) woff += wsum[w0];
  if (t < nb) bscan[t] = woff + incl - v;
  if (t == nb - 1) *total_out = woff + incl;     // row_ptr[m] = E
}

// ---- scan step 3: wave-scan + cross-wave offset (1 barrier) ----
__launch_bounds__(1024)
__global__ void scan_final(const int* __restrict__ rowcnt, const int* __restrict__ bscan,
                           int* __restrict__ row_ptr, int m){
  __shared__ int wsum[16];
  int t = threadIdx.x, lane = t & 63, wid = t >> 6;
  int idx = blockIdx.x * 1024 + t;
  int v = (idx < m) ? rowcnt[idx] : 0;
  int incl = v;
#pragma unroll
  for (int o = 1; o < 64; o <<= 1){
    int u = __shfl_up(incl, o);
    if (lane >= o) incl += u;
  }
  if (lane == 63) wsum[wid] = incl;
  __syncthreads();
  int woff = bscan[blockIdx.x];
  for (int w0 = 0; w0 < wid; ++w0) woff += wsum[w0];
  if (idx < m) row_ptr[idx] = woff + incl - v;   // exclusive
}

// ---- atomic-free bucket write: pos = row_ptr[key] + rank ----
__global__ void scatter_pos(const int* __restrict__ rel, const int* __restrict__ src,
                            const int* __restrict__ dst, const int* __restrict__ rank,
                            const int* __restrict__ row_ptr, int* __restrict__ payload, int E){
  int stride = gridDim.x * blockDim.x;
  for (int i = blockIdx.x * blockDim.x + threadIdx.x; i < E; i += stride){
    int key = (dst[i] << 3) | rel[i];
    payload[row_ptr[key] + rank[i]] = src[i];
  }
}

// ---- fused aggregate + transform: 128-node tile, 1024 threads (16 waves).
// Wave owns 8 nodes. Per relation r: 16-deep batched gathers -> h_r row in regs,
// B_r reg-prefetch; barrier; h_r+B_r -> LDS; barrier; 16 MFMA (K=128 chunk).
// h2 never goes to HBM. out = relu(acc) written NT.
// launch_bounds(1024,4): 128-VGPR cap -- (1024,8) forced a 64-VGPR cap and
// spilled ~440 MB of scratch per dispatch (R10 post-mortem).
__launch_bounds__(1024, 4)
__global__ void fused_agg_gemm(const unsigned short* __restrict__ xb,
                               const unsigned short* __restrict__ wbb,
                               const int* __restrict__ row_ptr8,
                               const int* __restrict__ payload,
                               float* __restrict__ out, int n, int m){
  __shared__ __align__(16) unsigned short lds_h[128 * LDB];   // 34 KB
  __shared__ __align__(16) unsigned short lds_b[128 * LDB];   // 34 KB
  const int t = threadIdx.x;
  const int wave = t >> 6, lane = t & 63;
  const int dbase = blockIdx.x << 7;
  const int nb = dbase + (wave << 3);          // wave's first node
  const int frow = lane & 15, kb = lane >> 4;
  const int mr = wave >> 2, nc = wave & 3;     // 4x4 wave grid, 32x32 out tile each

  // ---- once per wave: all 64 row boundaries + 3 payload windows ----
  int rowi = (nb << 3) + lane; if (rowi > m) rowi = m;   // OOB nodes -> cnt 0
  int pv = row_ptr8[rowi];
  int rowe = (nb << 3) + 64; if (rowe > m) rowe = m;
  int lastb = row_ptr8[rowe];
  int wbase = RL(pv, 0);
  int pl0 = payload[wbase + lane];             // spills past E land in row_ptr (safe)
  int pl1 = payload[wbase + 64 + lane];
  int pl2 = payload[wbase + 128 + lane];

  f32x4 acc[2][2];
#pragma unroll
  for (int rt = 0; rt < 2; ++rt)
#pragma unroll
    for (int jt = 0; jt < 2; ++jt)
      acc[rt][jt] = (f32x4){0.f, 0.f, 0.f, 0.f};

  for (int r = 0; r < RR; ++r){
    // segment [sg, sg+dg) per node for this r (all SGPR scalars)
    int sg[8], dg[8];
#pragma unroll
    for (int i = 0; i < 8; ++i){
      int bi = RL(pv, (i << 3) + r);
      int ei = ((i << 3) + r + 1) < 64 ? RL(pv, (i << 3) + r + 1) : lastb;
      sg[i] = bi - wbase;
      dg[i] = ei - bi;
    }
    int dmax = dg[0];
#pragma unroll
    for (int i = 1; i < 8; ++i) dmax = dg[i] > dmax ? dg[i] : dmax;

    float ax[8], ay[8];
#pragma unroll
    for (int i = 0; i < 8; ++i){ ax[i] = 0.f; ay[i] = 0.f; }

#define SRC(IDX) ((IDX) < 64 ? RL(pl0, (IDX)) : (IDX) < 128 ? RL(pl1, (IDX) - 64) \
                 : (IDX) < 192 ? RL(pl2, (IDX) - 128) : payload[wbase + (IDX)])

    for (int j = 0; j < dmax; j += 2){         // 2 ranks x 8 nodes: 16 loads in flight
      unsigned va[8], vb[8];
#pragma unroll
      for (int i = 0; i < 8; ++i){
        if (j < dg[i]){
          int s = SRC(sg[i] + j);
          va[i] = ((const unsigned*)(xb + ((size_t)s << 7)))[lane];
        }
        if (j + 1 < dg[i]){
          int s = SRC(sg[i] + j + 1);
          vb[i] = ((const unsigned*)(xb + ((size_t)s << 7)))[lane];
        }
      }
#pragma unroll
      for (int i = 0; i < 8; ++i){
        if (j < dg[i])    { ax[i] += bf2f(va[i] & 0xffffu); ay[i] += bf2f(va[i] >> 16); }
        if (j + 1 < dg[i]){ ax[i] += bf2f(vb[i] & 0xffffu); ay[i] += bf2f(vb[i] >> 16); }
      }
    }
#undef SRC

    // B_r prefetch to registers (issue before barrier; latency hides under it)
    const unsigned short* wp = wbb + (r << 14);
    const int brow = t >> 3, bcol = (t & 7) << 4;
    short8 pb0 = *(const short8*)(wp + brow * ED + bcol);
    short8 pb1 = *(const short8*)(wp + brow * ED + bcol + 8);

    __syncthreads();                           // prev MFMA done reading LDS
#pragma unroll
    for (int i = 0; i < 8; ++i){
      float sc = dg[i] > 0 ? 1.f / (float)dg[i] : 0.f;
      ((unsigned*)lds_h)[((wave << 3) + i) * (LDB / 2) + lane] = packbf(ay[i] * sc, ax[i] * sc);
    }
    *(short8*)&lds_b[brow * LDB + bcol] = pb0;
    *(short8*)&lds_b[brow * LDB + bcol + 8] = pb1;
    __syncthreads();                           // h_r, B_r ready

    // MFMA: 32x32 wave tile x K=128 chunk
#pragma unroll
    for (int ks = 0; ks < 4; ++ks){
      short8 a0 = *(const short8*)&lds_h[(mr * 32 + frow) * LDB + ks * 32 + kb * 8];
      short8 a1 = *(const short8*)&lds_h[(mr * 32 + 16 + frow) * LDB + ks * 32 + kb * 8];
      short8 b0 = *(const short8*)&lds_b[(nc * 32 + frow) * LDB + ks * 32 + kb * 8];
      short8 b1 = *(const short8*)&lds_b[(nc * 32 + 16 + frow) * LDB + ks * 32 + kb * 8];
      acc[0][0] = __builtin_amdgcn_mfma_f32_16x16x32_bf16(a0, b0, acc[0][0], 0, 0, 0);
      acc[0][1] = __builtin_amdgcn_mfma_f32_16x16x32_bf16(a0, b1, acc[0][1], 0, 0, 0);
      acc[1][0] = __builtin_amdgcn_mfma_f32_16x16x32_bf16(a1, b0, acc[1][0], 0, 0, 0);
      acc[1][1] = __builtin_amdgcn_mfma_f32_16x16x32_bf16(a1, b1, acc[1][1], 0, 0, 0);
    }
  }

  // ---- epilogue: D layout col = lane&15, row = (lane>>4)*4 + reg ----
  const int drow = (lane >> 4) << 2;
  const int dcol = lane & 15;
#pragma unroll
  for (int rt = 0; rt < 2; ++rt)
#pragma unroll
    for (int jt = 0; jt < 2; ++jt)
#pragma unroll
      for (int reg = 0; reg < 4; ++reg){
        int i = dbase + mr * 32 + rt * 16 + drow + reg;
        if (i < n)
          __builtin_nontemporal_store(fmaxf(acc[rt][jt][reg], 0.f),
                                      &out[(size_t)i * ED + nc * 32 + jt * 16 + dcol]);
      }
}

extern "C" void kernel_launch(void* const* d_in, const int* in_sizes, int n_in,
                              void* d_out, int out_size, void* d_ws, size_t ws_size,
                              hipStream_t stream){
  const float* x  = (const float*)d_in[0];
  const float* w  = (const float*)d_in[1];
  const int* erel = (const int*)d_in[2];
  const int* esrc = (const int*)d_in[3];
  const int* edst = (const int*)d_in[4];
  float* out = (float*)d_out;

  const int n = in_sizes[0] / ED;          // 100000
  const int E = in_sizes[2];               // 1600000
  const int m = n * RR;                    // 800000 CSR rows
  const int NB = (m + 1023) / 1024;        // 782 (must be <= 1024)

  // ---- workspace layout (256B-aligned segments) ----
  char* ws = (char*)d_ws;
  size_t off = 0;
  auto alloc = [&](size_t bytes) -> char* {
    char* p = ws + off;
    off += (bytes + 255) & ~(size_t)255;
    return p;
  };
  unsigned short* xb      = (unsigned short*)alloc((size_t)n * ED * 2);     // 25.6 MB
  unsigned short* wbb     = (unsigned short*)alloc((size_t)RR * ED * ED * 2); // 256 KB
  int*            payload = (int*)alloc((size_t)E * 4);                     // 6.4 MB
  int*            row_ptr = (int*)alloc((size_t)(m + 1) * 4);               // 3.2 MB (pads payload OOB reads)
  int*            rowcnt  = (int*)alloc((size_t)m * 4);
  int*            rank    = (int*)alloc((size_t)E * 4);                     // 6.4 MB
  int*            bsum    = (int*)alloc((size_t)NB * 4);
  int*            bscan   = (int*)alloc((size_t)NB * 4);
  if (off > ws_size || NB > 1024) return;

  (void)hipMemsetAsync(rowcnt, 0, (size_t)m * 4, stream);

  cast_bf16_vec<<<2048, 256, 0, stream>>>(x, xb, n * ED / 4);
  cast_bf16_vec<<<128, 256, 0, stream>>>(w, wbb, RR * ED * ED / 4);
  hist_rank    <<<2048, 256, 0, stream>>>(erel, edst, rowcnt, rank, E);
  scan_block_sum<<<NB, 1024, 0, stream>>>(rowcnt, bsum, m);
  scan_bsum_par<<<1, 1024, 0, stream>>>(bsum, bscan, NB, row_ptr + m);
  scan_final   <<<NB, 1024, 0, stream>>>(rowcnt, bscan, row_ptr, m);
  scatter_pos  <<<2048, 256, 0, stream>>>(erel, esrc, edst, rank, row_ptr, payload, E);
  fused_agg_gemm<<<(n + 127) / 128, 1024, 0, stream>>>(xb, wbb, row_ptr, payload, out, n, m);
}

// Round 12
// 285.784 us; speedup vs baseline: 1.3102x; 1.2855x over previous
//
#include <hip/hip_runtime.h>
#include <hip/hip_bf16.h>

#define ED 128
#define RR 8
#define KTOT (RR * ED)   // 1024
#define LDB 136          // LDS row stride in shorts (128 data + 8 pad)
#define CH 50048         // chunk size in nodes (391 * 128)

typedef __attribute__((ext_vector_type(8))) short short8;   // 8 x bf16
typedef __attribute__((ext_vector_type(4))) float f32x4;    // MFMA accumulator / NT f32x4
typedef __attribute__((ext_vector_type(4))) unsigned short u16x4;

#define RL(v, i) __builtin_amdgcn_readlane(v, i)

__device__ __forceinline__ unsigned short f2bf(float f){
  unsigned int u = __builtin_bit_cast(unsigned int, f);
  return (unsigned short)((u + 0x7fffu + ((u >> 16) & 1u)) >> 16);   // RNE
}
__device__ __forceinline__ float bf2f(unsigned int lo){
  return __builtin_bit_cast(float, lo << 16);
}
__device__ __forceinline__ unsigned int packbf(float hi, float lo){
  return ((unsigned int)f2bf(hi) << 16) | f2bf(lo);
}

// ---- cast f32 -> bf16, 4 at a time; NT load (x is read exactly once) ----
__global__ void cast_bf16_vec(const float* __restrict__ in, unsigned short* __restrict__ out, int n4){
  int stride = gridDim.x * blockDim.x;
  for (int i = blockIdx.x * blockDim.x + threadIdx.x; i < n4; i += stride){
    f32x4 v = __builtin_nontemporal_load((const f32x4*)(in + (size_t)i * 4));
    u16x4 o;
    o[0] = f2bf(v[0]); o[1] = f2bf(v[1]); o[2] = f2bf(v[2]); o[3] = f2bf(v[3]);
    *(u16x4*)(out + (size_t)i * 4) = o;          // normal store: xb/wbb stay cached
  }
}

// ---- single atomic pass: histogram + per-edge rank ----
__global__ void hist_rank(const int* __restrict__ rel, const int* __restrict__ dst,
                          int* __restrict__ rowcnt, int* __restrict__ rank, int E){
  int stride = gridDim.x * blockDim.x;
  for (int i = blockIdx.x * blockDim.x + threadIdx.x; i < E; i += stride)
    rank[i] = atomicAdd(&rowcnt[(dst[i] << 3) | rel[i]], 1);
}

// ---- scan step 1: per-block (1024) sums ----
__launch_bounds__(1024)
__global__ void scan_block_sum(const int* __restrict__ rowcnt, int* __restrict__ bsum, int m){
  __shared__ int lds[16];
  int t = threadIdx.x;
  int idx = blockIdx.x * 1024 + t;
  int v = (idx < m) ? rowcnt[idx] : 0;
#pragma unroll
  for (int o = 32; o > 0; o >>= 1) v += __shfl_down(v, o);
  if ((t & 63) == 0) lds[t >> 6] = v;
  __syncthreads();
  if (t == 0){
    int s = 0;
#pragma unroll
    for (int w = 0; w < 16; ++w) s += lds[w];
    bsum[blockIdx.x] = s;
  }
}

// ---- scan step 2: PARALLEL exclusive scan of block sums (nb <= 1024) ----
__launch_bounds__(1024)
__global__ void scan_bsum_par(const int* __restrict__ bsum, int* __restrict__ bscan,
                              int nb, int* __restrict__ total_out){
  __shared__ int wsum[16];
  int t = threadIdx.x, lane = t & 63, wid = t >> 6;
  int v = (t < nb) ? bsum[t] : 0;
  int incl = v;
#pragma unroll
  for (int o = 1; o < 64; o <<= 1){
    int u = __shfl_up(incl, o);
    if (lane >= o) incl += u;
  }
  if (lane == 63) wsum[wid] = incl;
  __syncthreads();
  int woff = 0;
  for (int w0 = 0; w0 < wid; ++w0) woff += wsum[w0];
  if (t < nb) bscan[t] = woff + incl - v;
  if (t == nb - 1) *total_out = woff + incl;     // row_ptr[m] = E
}

// ---- scan step 3: wave-scan + cross-wave offset (1 barrier) ----
__launch_bounds__(1024)
__global__ void scan_final(const int* __restrict__ rowcnt, const int* __restrict__ bscan,
                           int* __restrict__ row_ptr, int m){
  __shared__ int wsum[16];
  int t = threadIdx.x, lane = t & 63, wid = t >> 6;
  int idx = blockIdx.x * 1024 + t;
  int v = (idx < m) ? rowcnt[idx] : 0;
  int incl = v;
#pragma unroll
  for (int o = 1; o < 64; o <<= 1){
    int u = __shfl_up(incl, o);
    if (lane >= o) incl += u;
  }
  if (lane == 63) wsum[wid] = incl;
  __syncthreads();
  int woff = bscan[blockIdx.x];
  for (int w0 = 0; w0 < wid; ++w0) woff += wsum[w0];
  if (idx < m) row_ptr[idx] = woff + incl - v;   // exclusive
}

// ---- atomic-free bucket write: pos = row_ptr[key] + rank ----
__global__ void scatter_pos(const int* __restrict__ rel, const int* __restrict__ src,
                            const int* __restrict__ dst, const int* __restrict__ rank,
                            const int* __restrict__ row_ptr, int* __restrict__ payload, int E){
  int stride = gridDim.x * blockDim.x;
  for (int i = blockIdx.x * blockDim.x + threadIdx.x; i < E; i += stride){
    int key = (dst[i] << 3) | rel[i];
    payload[row_ptr[key] + rank[i]] = src[i];
  }
}

// ---- 1 wave per node in [d0,d1): flat window walk, 8 loads in flight,
//      binary scalar routing into 8 static accumulators.
//      h2buf stores are NORMAL (L3-resident chunk; gemm reads it next). ----
__launch_bounds__(256)
__global__ void row_agg(const unsigned short* __restrict__ xb,
                        const int* __restrict__ row_ptr8,
                        const int* __restrict__ payload,
                        unsigned short* __restrict__ h2buf, int d0, int d1){
  int d    = d0 + ((blockIdx.x * 256 + threadIdx.x) >> 6);
  int lane = threadIdx.x & 63;
  if (d >= d1) return;

  int p9 = 0;
  if (lane < 9) p9 = row_ptr8[(d << 3) + lane];    // 9 segment boundaries
  int b0  = RL(p9, 0);
  int o1  = RL(p9, 1) - b0;                        // all SGPRs -> scalar control flow
  int o2  = RL(p9, 2) - b0;
  int o3  = RL(p9, 3) - b0;
  int o4  = RL(p9, 4) - b0;
  int o5  = RL(p9, 5) - b0;
  int o6  = RL(p9, 6) - b0;
  int o7  = RL(p9, 7) - b0;
  int cnt = RL(p9, 8) - b0;

  float ax0=0.f,ay0=0.f,ax1=0.f,ay1=0.f,ax2=0.f,ay2=0.f,ax3=0.f,ay3=0.f;
  float ax4=0.f,ay4=0.f,ax5=0.f,ay5=0.f,ax6=0.f,ay6=0.f,ax7=0.f,ay7=0.f;

#define ROUTE(VV, IDX) { \
    float lo = bf2f((VV) & 0xffffu), hi = bf2f((VV) >> 16); \
    if ((IDX) < o4){ \
      if ((IDX) < o2){ if ((IDX) < o1){ ax0+=lo; ay0+=hi; } else { ax1+=lo; ay1+=hi; } } \
      else           { if ((IDX) < o3){ ax2+=lo; ay2+=hi; } else { ax3+=lo; ay3+=hi; } } \
    } else { \
      if ((IDX) < o6){ if ((IDX) < o5){ ax4+=lo; ay4+=hi; } else { ax5+=lo; ay5+=hi; } } \
      else           { if ((IDX) < o7){ ax6+=lo; ay6+=hi; } else { ax7+=lo; ay7+=hi; } } \
    } }

  if (cnt <= 64){                                  // fast path: one payload window
    int pl = payload[b0 + lane];                   // (reads past E land in row_ptr pad)
    int e = 0;
    for (; e + 8 <= cnt; e += 8){                  // 8 loads in flight before any use
      int s0 = RL(pl, e);
      int s1 = RL(pl, e + 1);
      int s2 = RL(pl, e + 2);
      int s3 = RL(pl, e + 3);
      int s4 = RL(pl, e + 4);
      int s5 = RL(pl, e + 5);
      int s6 = RL(pl, e + 6);
      int s7 = RL(pl, e + 7);
      unsigned int v0 = ((const unsigned int*)(xb + ((size_t)s0 << 7)))[lane];
      unsigned int v1 = ((const unsigned int*)(xb + ((size_t)s1 << 7)))[lane];
      unsigned int v2 = ((const unsigned int*)(xb + ((size_t)s2 << 7)))[lane];
      unsigned int v3 = ((const unsigned int*)(xb + ((size_t)s3 << 7)))[lane];
      unsigned int v4 = ((const unsigned int*)(xb + ((size_t)s4 << 7)))[lane];
      unsigned int v5 = ((const unsigned int*)(xb + ((size_t)s5 << 7)))[lane];
      unsigned int v6 = ((const unsigned int*)(xb + ((size_t)s6 << 7)))[lane];
      unsigned int v7 = ((const unsigned int*)(xb + ((size_t)s7 << 7)))[lane];
      ROUTE(v0, e)
      ROUTE(v1, e + 1)
      ROUTE(v2, e + 2)
      ROUTE(v3, e + 3)
      ROUTE(v4, e + 4)
      ROUTE(v5, e + 5)
      ROUTE(v6, e + 6)
      ROUTE(v7, e + 7)
    }
    for (; e < cnt; ++e){                          // tail (<=7 edges)
      int s = RL(pl, e);
      unsigned int v = ((const unsigned int*)(xb + ((size_t)s << 7)))[lane];
      ROUTE(v, e)
    }
  } else {                                         // rare fat node: serial path
    for (int e = 0; e < cnt; ++e){
      int s = __builtin_amdgcn_readfirstlane(payload[b0 + e]);
      unsigned int v = ((const unsigned int*)(xb + ((size_t)s << 7)))[lane];
      ROUTE(v, e)
    }
  }
#undef ROUTE

  int c0 = o1, c1 = o2 - o1, c2 = o3 - o2, c3 = o4 - o3;
  int c4 = o5 - o4, c5 = o6 - o5, c6 = o7 - o6, c7 = cnt - o7;
  unsigned int* hp = (unsigned int*)h2buf + ((size_t)(d - d0) << 9) + lane;
  float sc;
  sc = c0 ? 1.f / (float)c0 : 0.f; hp[0]   = packbf(ay0*sc, ax0*sc);
  sc = c1 ? 1.f / (float)c1 : 0.f; hp[64]  = packbf(ay1*sc, ax1*sc);
  sc = c2 ? 1.f / (float)c2 : 0.f; hp[128] = packbf(ay2*sc, ax2*sc);
  sc = c3 ? 1.f / (float)c3 : 0.f; hp[192] = packbf(ay3*sc, ax3*sc);
  sc = c4 ? 1.f / (float)c4 : 0.f; hp[256] = packbf(ay4*sc, ax4*sc);
  sc = c5 ? 1.f / (float)c5 : 0.f; hp[320] = packbf(ay5*sc, ax5*sc);
  sc = c6 ? 1.f / (float)c6 : 0.f; hp[384] = packbf(ay6*sc, ax6*sc);
  sc = c7 ? 1.f / (float)c7 : 0.f; hp[448] = packbf(ay7*sc, ax7*sc);
}

// ---- out[d][j] = relu( sum_r sum_kk h2buf[d-d0][r*128+kk] * W[r][j][kk] ) ----
// 128x128 block tile, 4 waves 2x2, A+B LDS-staged per r, reg-prefetch pipeline.
// h2buf loads NORMAL (L3 hits); out stores NT.
__launch_bounds__(256)
__global__ void gemm_out(const unsigned short* __restrict__ h2buf,
                         const unsigned short* __restrict__ wbb,
                         float* __restrict__ out, int d0, int d1){
  __shared__ __align__(16) unsigned short lds_a[128 * LDB];   // 34.8 KB
  __shared__ __align__(16) unsigned short lds_b[128 * LDB];   // 34.8 KB
  const int t = threadIdx.x;
  const int wave = t >> 6, lane = t & 63;
  const int wr = wave >> 1, wc = wave & 1;        // 2x2 wave grid
  const int dbase = d0 + blockIdx.x * 128;
  const int frow = lane & 15, kb = lane >> 4;

  f32x4 acc[4][4];
#pragma unroll
  for (int rt = 0; rt < 4; ++rt)
#pragma unroll
    for (int jt = 0; jt < 4; ++jt)
      acc[rt][jt] = (f32x4){0.f, 0.f, 0.f, 0.f};

  short8 pa[8], pb[8];
  // prefetch chunk r = 0 into registers
#pragma unroll
  for (int p = 0; p < 8; ++p){
    int q = p * 256 + t;
    int row = q >> 4, col = q & 15;
    int gr = dbase + row; if (gr >= d1) gr = d1 - 1;
    pa[p] = *(const short8*)(h2buf + (size_t)(gr - d0) * KTOT + col * 8);
    pb[p] = *(const short8*)(wbb + row * ED + col * 8);
  }

  for (int r = 0; r < RR; ++r){
    __syncthreads();                               // prev-iter LDS readers done
    // commit prefetched chunk to LDS
#pragma unroll
    for (int p = 0; p < 8; ++p){
      int q = p * 256 + t;
      int row = q >> 4, col = q & 15;
      *(short8*)&lds_a[row * LDB + col * 8] = pa[p];
      *(short8*)&lds_b[row * LDB + col * 8] = pb[p];
    }
    __syncthreads();

    // issue next chunk's global loads; latency hides under the MFMA block below
    if (r + 1 < RR){
#pragma unroll
      for (int p = 0; p < 8; ++p){
        int q = p * 256 + t;
        int row = q >> 4, col = q & 15;
        int gr = dbase + row; if (gr >= d1) gr = d1 - 1;
        pa[p] = *(const short8*)(h2buf + (size_t)(gr - d0) * KTOT + (r + 1) * ED + col * 8);
        pb[p] = *(const short8*)(wbb + (size_t)(r + 1) * ED * ED + row * ED + col * 8);
      }
    }

    short8 a[4][4], b[4][4];
#pragma unroll
    for (int rt = 0; rt < 4; ++rt)
#pragma unroll
      for (int ks = 0; ks < 4; ++ks)
        a[rt][ks] = *(const short8*)&lds_a[(wr * 64 + rt * 16 + frow) * LDB + ks * 32 + kb * 8];
#pragma unroll
    for (int jt = 0; jt < 4; ++jt)
#pragma unroll
      for (int ks = 0; ks < 4; ++ks)
        b[jt][ks] = *(const short8*)&lds_b[(wc * 64 + jt * 16 + frow) * LDB + ks * 32 + kb * 8];
#pragma unroll
    for (int rt = 0; rt < 4; ++rt)
#pragma unroll
      for (int jt = 0; jt < 4; ++jt)
#pragma unroll
        for (int ks = 0; ks < 4; ++ks)
          acc[rt][jt] = __builtin_amdgcn_mfma_f32_16x16x32_bf16(a[rt][ks], b[jt][ks], acc[rt][jt], 0, 0, 0);
  }

  // D layout: col = lane&15, row = (lane>>4)*4 + reg
  const int drow = (lane >> 4) * 4;
  const int dcol = lane & 15;
#pragma unroll
  for (int rt = 0; rt < 4; ++rt)
#pragma unroll
    for (int jt = 0; jt < 4; ++jt)
#pragma unroll
      for (int reg = 0; reg < 4; ++reg){
        int i = dbase + wr * 64 + rt * 16 + drow + reg;
        if (i < d1)
          __builtin_nontemporal_store(fmaxf(acc[rt][jt][reg], 0.f),
                                      &out[(size_t)i * ED + wc * 64 + jt * 16 + dcol]);
      }
}

extern "C" void kernel_launch(void* const* d_in, const int* in_sizes, int n_in,
                              void* d_out, int out_size, void* d_ws, size_t ws_size,
                              hipStream_t stream){
  const float* x  = (const float*)d_in[0];
  const float* w  = (const float*)d_in[1];
  const int* erel = (const int*)d_in[2];
  const int* esrc = (const int*)d_in[3];
  const int* edst = (const int*)d_in[4];
  float* out = (float*)d_out;

  const int n = in_sizes[0] / ED;          // 100000
  const int E = in_sizes[2];               // 1600000
  const int m = n * RR;                    // 800000 CSR rows
  const int NB = (m + 1023) / 1024;        // 782 (must be <= 1024)

  // ---- workspace layout (256B-aligned segments) ----
  char* ws = (char*)d_ws;
  size_t off = 0;
  auto alloc = [&](size_t bytes) -> char* {
    char* p = ws + off;
    off += (bytes + 255) & ~(size_t)255;
    return p;
  };
  unsigned short* h2buf   = (unsigned short*)alloc((size_t)CH * KTOT * 2);  // 102.5 MB (reused per chunk)
  unsigned short* xb      = (unsigned short*)alloc((size_t)n * ED * 2);     // 25.6 MB
  unsigned short* wbb     = (unsigned short*)alloc((size_t)RR * ED * ED * 2); // 256 KB
  int*            payload = (int*)alloc((size_t)E * 4);                     // 6.4 MB
  int*            row_ptr = (int*)alloc((size_t)(m + 1) * 4);               // 3.2 MB (pads payload OOB prefetch)
  int*            rowcnt  = (int*)alloc((size_t)m * 4);
  int*            rank    = (int*)alloc((size_t)E * 4);                     // 6.4 MB
  int*            bsum    = (int*)alloc((size_t)NB * 4);
  int*            bscan   = (int*)alloc((size_t)NB * 4);
  if (off > ws_size || NB > 1024) return;

  (void)hipMemsetAsync(rowcnt, 0, (size_t)m * 4, stream);

  cast_bf16_vec<<<2048, 256, 0, stream>>>(x, xb, n * ED / 4);
  cast_bf16_vec<<<128, 256, 0, stream>>>(w, wbb, RR * ED * ED / 4);
  hist_rank    <<<2048, 256, 0, stream>>>(erel, edst, rowcnt, rank, E);
  scan_block_sum<<<NB, 1024, 0, stream>>>(rowcnt, bsum, m);
  scan_bsum_par<<<1, 1024, 0, stream>>>(bsum, bscan, NB, row_ptr + m);
  scan_final   <<<NB, 1024, 0, stream>>>(rowcnt, bscan, row_ptr, m);
  scatter_pos  <<<2048, 256, 0, stream>>>(erel, esrc, edst, rank, row_ptr, payload, E);

  // ---- chunked agg->gemm: h2 chunk stays L3-resident, never round-trips HBM ----
  for (int c = 0; c < 2; ++c){
    int d0 = c * CH;
    int d1 = (c == 0) ? CH : n;
    int nodes = d1 - d0;
    row_agg <<<(nodes + 3) / 4, 256, 0, stream>>>(xb, row_ptr, payload, h2buf, d0, d1);
    gemm_out<<<(nodes + 127) / 128, 256, 0, stream>>>(h2buf, wbb, out, d0, d1);
  }
}

// Round 13
// 283.770 us; speedup vs baseline: 1.3195x; 1.0071x over previous
//
#include <hip/hip_runtime.h>
#include <hip/hip_bf16.h>

#define ED 128
#define RR 8
#define KTOT (RR * ED)   // 1024
#define LDB 136          // LDS row stride in shorts (128 data + 8 pad)
#define CH 50048         // chunk size in nodes (391 * 128)
#define HB 1568          // fused_front blocks: histogram partition
#define CB 1600          // fused_front blocks: x-cast partition
#define WB 8             // fused_front blocks: w-cast partition

typedef __attribute__((ext_vector_type(8))) short short8;   // 8 x bf16
typedef __attribute__((ext_vector_type(4))) float f32x4;    // MFMA accumulator / NT f32x4
typedef __attribute__((ext_vector_type(4))) unsigned short u16x4;

#define RL(v, i) __builtin_amdgcn_readlane(v, i)

__device__ __forceinline__ unsigned short f2bf(float f){
  unsigned int u = __builtin_bit_cast(unsigned int, f);
  return (unsigned short)((u + 0x7fffu + ((u >> 16) & 1u)) >> 16);   // RNE
}
__device__ __forceinline__ float bf2f(unsigned int lo){
  return __builtin_bit_cast(float, lo << 16);
}
__device__ __forceinline__ unsigned int packbf(float hi, float lo){
  return ((unsigned int)f2bf(hi) << 16) | f2bf(lo);
}
__device__ __forceinline__ void cast4(const float* __restrict__ in,
                                      unsigned short* __restrict__ out, int i){
  f32x4 v = __builtin_nontemporal_load((const f32x4*)(in + (size_t)i * 4));
  u16x4 o;
  o[0] = f2bf(v[0]); o[1] = f2bf(v[1]); o[2] = f2bf(v[2]); o[3] = f2bf(v[3]);
  *(u16x4*)(out + (size_t)i * 4) = o;
}

// ---- fused front: [0,HB) packed histogram+rank, [HB,HB+CB) cast x, rest cast w ----
// Packed counters: rowcnt[key>>1] holds two 16-bit degrees (lo = even key, hi = odd).
// Halves the atomic write-through line footprint (R12: 56 MB WRITE for 9.6 MB of stores).
__global__ void fused_front(const int* __restrict__ rel, const int* __restrict__ dst,
                            unsigned int* __restrict__ rowcnt, int* __restrict__ rank,
                            const float* __restrict__ x, unsigned short* __restrict__ xb, int nx4,
                            const float* __restrict__ w, unsigned short* __restrict__ wb, int nw4,
                            int E){
  int b = blockIdx.x;
  if (b < HB){
    int tid = b * 256 + threadIdx.x;
    int nthr = HB * 256;
    int E4 = E >> 2;                               // E % 4 == 0
    for (int i = tid; i < E4; i += nthr){
      int4 r4 = ((const int4*)rel)[i];
      int4 d4 = ((const int4*)dst)[i];
      int k0 = (d4.x << 3) | r4.x;
      int k1 = (d4.y << 3) | r4.y;
      int k2 = (d4.z << 3) | r4.z;
      int k3 = (d4.w << 3) | r4.w;
      unsigned o0 = atomicAdd(&rowcnt[k0 >> 1], (k0 & 1) ? 0x10000u : 1u);
      unsigned o1 = atomicAdd(&rowcnt[k1 >> 1], (k1 & 1) ? 0x10000u : 1u);
      unsigned o2 = atomicAdd(&rowcnt[k2 >> 1], (k2 & 1) ? 0x10000u : 1u);
      unsigned o3 = atomicAdd(&rowcnt[k3 >> 1], (k3 & 1) ? 0x10000u : 1u);
      int4 rk;
      rk.x = (k0 & 1) ? (int)(o0 >> 16) : (int)(o0 & 0xffffu);
      rk.y = (k1 & 1) ? (int)(o1 >> 16) : (int)(o1 & 0xffffu);
      rk.z = (k2 & 1) ? (int)(o2 >> 16) : (int)(o2 & 0xffffu);
      rk.w = (k3 & 1) ? (int)(o3 >> 16) : (int)(o3 & 0xffffu);
      ((int4*)rank)[i] = rk;
    }
  } else if (b < HB + CB){
    int tid = (b - HB) * 256 + threadIdx.x;
    int nthr = CB * 256;
    for (int i = tid; i < nx4; i += nthr) cast4(x, xb, i);
  } else {
    int tid = (b - HB - CB) * 256 + threadIdx.x;
    int nthr = WB * 256;
    for (int i = tid; i < nw4; i += nthr) cast4(w, wb, i);
  }
}

// ---- scan step 1: per-block (1024) sums over PACKED counters ----
__launch_bounds__(1024)
__global__ void scan_block_sum(const unsigned int* __restrict__ rowcnt, int* __restrict__ bsum, int mm){
  __shared__ int lds[16];
  int t = threadIdx.x;
  int idx = blockIdx.x * 1024 + t;
  unsigned pv = (idx < mm) ? rowcnt[idx] : 0u;
  int v = (int)(pv & 0xffffu) + (int)(pv >> 16);
#pragma unroll
  for (int o = 32; o > 0; o >>= 1) v += __shfl_down(v, o);
  if ((t & 63) == 0) lds[t >> 6] = v;
  __syncthreads();
  if (t == 0){
    int s = 0;
#pragma unroll
    for (int w = 0; w < 16; ++w) s += lds[w];
    bsum[blockIdx.x] = s;
  }
}

// ---- scan step 2: PARALLEL exclusive scan of block sums (nb <= 1024) ----
__launch_bounds__(1024)
__global__ void scan_bsum_par(const int* __restrict__ bsum, int* __restrict__ bscan,
                              int nb, int* __restrict__ total_out){
  __shared__ int wsum[16];
  int t = threadIdx.x, lane = t & 63, wid = t >> 6;
  int v = (t < nb) ? bsum[t] : 0;
  int incl = v;
#pragma unroll
  for (int o = 1; o < 64; o <<= 1){
    int u = __shfl_up(incl, o);
    if (lane >= o) incl += u;
  }
  if (lane == 63) wsum[wid] = incl;
  __syncthreads();
  int woff = 0;
  for (int w0 = 0; w0 < wid; ++w0) woff += wsum[w0];
  if (t < nb) bscan[t] = woff + incl - v;
  if (t == nb - 1) *total_out = woff + incl;     // row_ptr[m] = E
}

// ---- scan step 3: packed wave-scan; emits BOTH row_ptr entries per word ----
__launch_bounds__(1024)
__global__ void scan_final(const unsigned int* __restrict__ rowcnt, const int* __restrict__ bscan,
                           int* __restrict__ row_ptr, int mm){
  __shared__ int wsum[16];
  int t = threadIdx.x, lane = t & 63, wid = t >> 6;
  int idx = blockIdx.x * 1024 + t;
  unsigned pv = (idx < mm) ? rowcnt[idx] : 0u;
  int lo = (int)(pv & 0xffffu);
  int v = lo + (int)(pv >> 16);
  int incl = v;
#pragma unroll
  for (int o = 1; o < 64; o <<= 1){
    int u = __shfl_up(incl, o);
    if (lane >= o) incl += u;
  }
  if (lane == 63) wsum[wid] = incl;
  __syncthreads();
  int woff = bscan[blockIdx.x];
  for (int w0 = 0; w0 < wid; ++w0) woff += wsum[w0];
  if (idx < mm){
    int ex = woff + incl - v;                    // exclusive over packed pairs
    row_ptr[2 * idx]     = ex;                   // even key (lo half)
    row_ptr[2 * idx + 1] = ex + lo;              // odd key (hi half)
  }
}

// ---- atomic-free bucket write, 4 edges/thread: pos = row_ptr[key] + rank ----
__global__ void scatter_pos(const int* __restrict__ rel, const int* __restrict__ src,
                            const int* __restrict__ dst, const int* __restrict__ rank,
                            const int* __restrict__ row_ptr, int* __restrict__ payload, int E){
  int tid = blockIdx.x * 256 + threadIdx.x;
  int nthr = gridDim.x * 256;
  int E4 = E >> 2;
  for (int i = tid; i < E4; i += nthr){
    int4 r4 = ((const int4*)rel)[i];
    int4 s4 = ((const int4*)src)[i];
    int4 d4 = ((const int4*)dst)[i];
    int4 k4 = ((const int4*)rank)[i];
    int p0 = row_ptr[(d4.x << 3) | r4.x] + k4.x;
    int p1 = row_ptr[(d4.y << 3) | r4.y] + k4.y;
    int p2 = row_ptr[(d4.z << 3) | r4.z] + k4.z;
    int p3 = row_ptr[(d4.w << 3) | r4.w] + k4.w;
    payload[p0] = s4.x;
    payload[p1] = s4.y;
    payload[p2] = s4.z;
    payload[p3] = s4.w;
  }
}

// ---- 1 wave per node in [d0,d1): flat window walk, 8 loads in flight,
//      binary scalar routing into 8 static accumulators. ----
__launch_bounds__(256)
__global__ void row_agg(const unsigned short* __restrict__ xb,
                        const int* __restrict__ row_ptr8,
                        const int* __restrict__ payload,
                        unsigned short* __restrict__ h2buf, int d0, int d1){
  int d    = d0 + ((blockIdx.x * 256 + threadIdx.x) >> 6);
  int lane = threadIdx.x & 63;
  if (d >= d1) return;

  int p9 = 0;
  if (lane < 9) p9 = row_ptr8[(d << 3) + lane];    // 9 segment boundaries
  int b0  = RL(p9, 0);
  int o1  = RL(p9, 1) - b0;                        // all SGPRs -> scalar control flow
  int o2  = RL(p9, 2) - b0;
  int o3  = RL(p9, 3) - b0;
  int o4  = RL(p9, 4) - b0;
  int o5  = RL(p9, 5) - b0;
  int o6  = RL(p9, 6) - b0;
  int o7  = RL(p9, 7) - b0;
  int cnt = RL(p9, 8) - b0;

  float ax0=0.f,ay0=0.f,ax1=0.f,ay1=0.f,ax2=0.f,ay2=0.f,ax3=0.f,ay3=0.f;
  float ax4=0.f,ay4=0.f,ax5=0.f,ay5=0.f,ax6=0.f,ay6=0.f,ax7=0.f,ay7=0.f;

#define ROUTE(VV, IDX) { \
    float lo = bf2f((VV) & 0xffffu), hi = bf2f((VV) >> 16); \
    if ((IDX) < o4){ \
      if ((IDX) < o2){ if ((IDX) < o1){ ax0+=lo; ay0+=hi; } else { ax1+=lo; ay1+=hi; } } \
      else           { if ((IDX) < o3){ ax2+=lo; ay2+=hi; } else { ax3+=lo; ay3+=hi; } } \
    } else { \
      if ((IDX) < o6){ if ((IDX) < o5){ ax4+=lo; ay4+=hi; } else { ax5+=lo; ay5+=hi; } } \
      else           { if ((IDX) < o7){ ax6+=lo; ay6+=hi; } else { ax7+=lo; ay7+=hi; } } \
    } }

  if (cnt <= 64){                                  // fast path: one payload window
    int pl = payload[b0 + lane];                   // (reads past E land in row_ptr pad)
    int e = 0;
    for (; e + 8 <= cnt; e += 8){                  // 8 loads in flight before any use
      int s0 = RL(pl, e);
      int s1 = RL(pl, e + 1);
      int s2 = RL(pl, e + 2);
      int s3 = RL(pl, e + 3);
      int s4 = RL(pl, e + 4);
      int s5 = RL(pl, e + 5);
      int s6 = RL(pl, e + 6);
      int s7 = RL(pl, e + 7);
      unsigned int v0 = ((const unsigned int*)(xb + ((size_t)s0 << 7)))[lane];
      unsigned int v1 = ((const unsigned int*)(xb + ((size_t)s1 << 7)))[lane];
      unsigned int v2 = ((const unsigned int*)(xb + ((size_t)s2 << 7)))[lane];
      unsigned int v3 = ((const unsigned int*)(xb + ((size_t)s3 << 7)))[lane];
      unsigned int v4 = ((const unsigned int*)(xb + ((size_t)s4 << 7)))[lane];
      unsigned int v5 = ((const unsigned int*)(xb + ((size_t)s5 << 7)))[lane];
      unsigned int v6 = ((const unsigned int*)(xb + ((size_t)s6 << 7)))[lane];
      unsigned int v7 = ((const unsigned int*)(xb + ((size_t)s7 << 7)))[lane];
      ROUTE(v0, e)
      ROUTE(v1, e + 1)
      ROUTE(v2, e + 2)
      ROUTE(v3, e + 3)
      ROUTE(v4, e + 4)
      ROUTE(v5, e + 5)
      ROUTE(v6, e + 6)
      ROUTE(v7, e + 7)
    }
    for (; e < cnt; ++e){                          // tail (<=7 edges)
      int s = RL(pl, e);
      unsigned int v = ((const unsigned int*)(xb + ((size_t)s << 7)))[lane];
      ROUTE(v, e)
    }
  } else {                                         // rare fat node: serial path
    for (int e = 0; e < cnt; ++e){
      int s = __builtin_amdgcn_readfirstlane(payload[b0 + e]);
      unsigned int v = ((const unsigned int*)(xb + ((size_t)s << 7)))[lane];
      ROUTE(v, e)
    }
  }
#undef ROUTE

  int c0 = o1, c1 = o2 - o1, c2 = o3 - o2, c3 = o4 - o3;
  int c4 = o5 - o4, c5 = o6 - o5, c6 = o7 - o6, c7 = cnt - o7;
  unsigned int* hp = (unsigned int*)h2buf + ((size_t)(d - d0) << 9) + lane;
  float sc;
  sc = c0 ? 1.f / (float)c0 : 0.f; hp[0]   = packbf(ay0*sc, ax0*sc);
  sc = c1 ? 1.f / (float)c1 : 0.f; hp[64]  = packbf(ay1*sc, ax1*sc);
  sc = c2 ? 1.f / (float)c2 : 0.f; hp[128] = packbf(ay2*sc, ax2*sc);
  sc = c3 ? 1.f / (float)c3 : 0.f; hp[192] = packbf(ay3*sc, ax3*sc);
  sc = c4 ? 1.f / (float)c4 : 0.f; hp[256] = packbf(ay4*sc, ax4*sc);
  sc = c5 ? 1.f / (float)c5 : 0.f; hp[320] = packbf(ay5*sc, ax5*sc);
  sc = c6 ? 1.f / (float)c6 : 0.f; hp[384] = packbf(ay6*sc, ax6*sc);
  sc = c7 ? 1.f / (float)c7 : 0.f; hp[448] = packbf(ay7*sc, ax7*sc);
}

// ---- out[d][j] = relu( sum_r sum_kk h2buf[d-d0][r*128+kk] * W[r][j][kk] ) ----
// 128x128 block tile, 4 waves 2x2, A+B LDS-staged per r, reg-prefetch pipeline.
__launch_bounds__(256)
__global__ void gemm_out(const unsigned short* __restrict__ h2buf,
                         const unsigned short* __restrict__ wbb,
                         float* __restrict__ out, int d0, int d1){
  __shared__ __align__(16) unsigned short lds_a[128 * LDB];   // 34.8 KB
  __shared__ __align__(16) unsigned short lds_b[128 * LDB];   // 34.8 KB
  const int t = threadIdx.x;
  const int wave = t >> 6, lane = t & 63;
  const int wr = wave >> 1, wc = wave & 1;        // 2x2 wave grid
  const int dbase = d0 + blockIdx.x * 128;
  const int frow = lane & 15, kb = lane >> 4;

  f32x4 acc[4][4];
#pragma unroll
  for (int rt = 0; rt < 4; ++rt)
#pragma unroll
    for (int jt = 0; jt < 4; ++jt)
      acc[rt][jt] = (f32x4){0.f, 0.f, 0.f, 0.f};

  short8 pa[8], pb[8];
#pragma unroll
  for (int p = 0; p < 8; ++p){
    int q = p * 256 + t;
    int row = q >> 4, col = q & 15;
    int gr = dbase + row; if (gr >= d1) gr = d1 - 1;
    pa[p] = *(const short8*)(h2buf + (size_t)(gr - d0) * KTOT + col * 8);
    pb[p] = *(const short8*)(wbb + row * ED + col * 8);
  }

  for (int r = 0; r < RR; ++r){
    __syncthreads();                               // prev-iter LDS readers done
#pragma unroll
    for (int p = 0; p < 8; ++p){
      int q = p * 256 + t;
      int row = q >> 4, col = q & 15;
      *(short8*)&lds_a[row * LDB + col * 8] = pa[p];
      *(short8*)&lds_b[row * LDB + col * 8] = pb[p];
    }
    __syncthreads();

    if (r + 1 < RR){
#pragma unroll
      for (int p = 0; p < 8; ++p){
        int q = p * 256 + t;
        int row = q >> 4, col = q & 15;
        int gr = dbase + row; if (gr >= d1) gr = d1 - 1;
        pa[p] = *(const short8*)(h2buf + (size_t)(gr - d0) * KTOT + (r + 1) * ED + col * 8);
        pb[p] = *(const short8*)(wbb + (size_t)(r + 1) * ED * ED + row * ED + col * 8);
      }
    }

    short8 a[4][4], b[4][4];
#pragma unroll
    for (int rt = 0; rt < 4; ++rt)
#pragma unroll
      for (int ks = 0; ks < 4; ++ks)
        a[rt][ks] = *(const short8*)&lds_a[(wr * 64 + rt * 16 + frow) * LDB + ks * 32 + kb * 8];
#pragma unroll
    for (int jt = 0; jt < 4; ++jt)
#pragma unroll
      for (int ks = 0; ks < 4; ++ks)
        b[jt][ks] = *(const short8*)&lds_b[(wc * 64 + jt * 16 + frow) * LDB + ks * 32 + kb * 8];
#pragma unroll
    for (int rt = 0; rt < 4; ++rt)
#pragma unroll
      for (int jt = 0; jt < 4; ++jt)
#pragma unroll
        for (int ks = 0; ks < 4; ++ks)
          acc[rt][jt] = __builtin_amdgcn_mfma_f32_16x16x32_bf16(a[rt][ks], b[jt][ks], acc[rt][jt], 0, 0, 0);
  }

  // D layout: col = lane&15, row = (lane>>4)*4 + reg
  const int drow = (lane >> 4) * 4;
  const int dcol = lane & 15;
#pragma unroll
  for (int rt = 0; rt < 4; ++rt)
#pragma unroll
    for (int jt = 0; jt < 4; ++jt)
#pragma unroll
      for (int reg = 0; reg < 4; ++reg){
        int i = dbase + wr * 64 + rt * 16 + drow + reg;
        if (i < d1)
          __builtin_nontemporal_store(fmaxf(acc[rt][jt][reg], 0.f),
                                      &out[(size_t)i * ED + wc * 64 + jt * 16 + dcol]);
      }
}

extern "C" void kernel_launch(void* const* d_in, const int* in_sizes, int n_in,
                              void* d_out, int out_size, void* d_ws, size_t ws_size,
                              hipStream_t stream){
  const float* x  = (const float*)d_in[0];
  const float* w  = (const float*)d_in[1];
  const int* erel = (const int*)d_in[2];
  const int* esrc = (const int*)d_in[3];
  const int* edst = (const int*)d_in[4];
  float* out = (float*)d_out;

  const int n = in_sizes[0] / ED;          // 100000
  const int E = in_sizes[2];               // 1600000
  const int m = n * RR;                    // 800000 CSR rows
  const int mm = m / 2;                    // 400000 packed counter words
  const int NB = (mm + 1023) / 1024;       // 391 (must be <= 1024)

  // ---- workspace layout (256B-aligned segments) ----
  char* ws = (char*)d_ws;
  size_t off = 0;
  auto alloc = [&](size_t bytes) -> char* {
    char* p = ws + off;
    off += (bytes + 255) & ~(size_t)255;
    return p;
  };
  unsigned short* h2buf   = (unsigned short*)alloc((size_t)CH * KTOT * 2);  // 102.5 MB (reused per chunk)
  unsigned short* xb      = (unsigned short*)alloc((size_t)n * ED * 2);     // 25.6 MB
  unsigned short* wbb     = (unsigned short*)alloc((size_t)RR * ED * ED * 2); // 256 KB
  int*            payload = (int*)alloc((size_t)E * 4);                     // 6.4 MB
  int*            row_ptr = (int*)alloc((size_t)(m + 1) * 4);               // 3.2 MB (pads payload OOB prefetch)
  unsigned int*   rowcnt  = (unsigned int*)alloc((size_t)mm * 4);           // 1.6 MB packed
  int*            rank    = (int*)alloc((size_t)E * 4);                     // 6.4 MB
  int*            bsum    = (int*)alloc((size_t)NB * 4);
  int*            bscan   = (int*)alloc((size_t)NB * 4);
  if (off > ws_size || NB > 1024) return;

  (void)hipMemsetAsync(rowcnt, 0, (size_t)mm * 4, stream);

  fused_front  <<<HB + CB + WB, 256, 0, stream>>>(erel, edst, rowcnt, rank,
                                                  x, xb, n * ED / 4,
                                                  w, wbb, RR * ED * ED / 4, E);
  scan_block_sum<<<NB, 1024, 0, stream>>>(rowcnt, bsum, mm);
  scan_bsum_par<<<1, 1024, 0, stream>>>(bsum, bscan, NB, row_ptr + m);
  scan_final   <<<NB, 1024, 0, stream>>>(rowcnt, bscan, row_ptr, mm);
  scatter_pos  <<<1568, 256, 0, stream>>>(erel, esrc, edst, rank, row_ptr, payload, E);

  // ---- chunked agg->gemm: h2 chunk stays L3-resident, never round-trips HBM ----
  for (int c = 0; c < 2; ++c){
    int d0 = c * CH;
    int d1 = (c == 0) ? CH : n;
    int nodes = d1 - d0;
    row_agg <<<(nodes + 3) / 4, 256, 0, stream>>>(xb, row_ptr, payload, h2buf, d0, d1);
    gemm_out<<<(nodes + 127) / 128, 256, 0, stream>>>(h2buf, wbb, out, d0, d1);
  }
}